// Round 1
// baseline (485.150 us; speedup 1.0000x reference)
//
#include <hip/hip_runtime.h>

// stepSSM: B rows, each: fc1 -> 4x(complex SSM step -> leaky_relu(0.125) -> 2x2 fc) -> fc10.
// Memory-bound: ~536 B/row compulsory traffic. One thread per row, weights in LDS.

constexpr float NEG_SLOPE = 0.125f;

__global__ __launch_bounds__(256) void ssm_fused(
    const float* __restrict__ x,
    const float* __restrict__ states,
    const float* __restrict__ fc1_w,
    const float* __restrict__ fc1_b,
    const float* __restrict__ fc_w,
    const float* __restrict__ fc_b,
    const float* __restrict__ A,
    const float* __restrict__ Bm,
    const float* __restrict__ Cm,
    const float* __restrict__ Dm,
    float* __restrict__ out_h,
    float* __restrict__ out_states,
    int B)
{
    // LDS weight cache layout:
    // [0..7]   fc1_w [2,4]
    // [8..9]   fc1_b [2]
    // [10..29] fc_w  [5,2,2]
    // [30..39] fc_b  [5,2]
    // [40..103]  A  [4,2,4,2]
    // [104..167] Bm [4,2,4,2]
    // [168..231] C  [4,1,2,4,2]
    // [232..239] D  [4,1,2]
    __shared__ float w[240];
    const int t = threadIdx.x;
    if (t < 240) {
        float v;
        if (t < 8)        v = fc1_w[t];
        else if (t < 10)  v = fc1_b[t - 8];
        else if (t < 30)  v = fc_w[t - 10];
        else if (t < 40)  v = fc_b[t - 30];
        else if (t < 104) v = A[t - 40];
        else if (t < 168) v = Bm[t - 104];
        else if (t < 232) v = Cm[t - 168];
        else              v = Dm[t - 232];
        w[t] = v;
    }
    __syncthreads();

    const int n = blockIdx.x * 256 + t;
    if (n >= B) return;

    const float4 xv = ((const float4*)x)[n];
    float h0 = w[8] + xv.x * w[0] + xv.y * w[1] + xv.z * w[2] + xv.w * w[3];
    float h1 = w[9] + xv.x * w[4] + xv.y * w[5] + xv.z * w[6] + xv.w * w[7];

    const float* wA  = w + 40;
    const float* wB  = w + 104;
    const float* wC  = w + 168;
    const float* wD  = w + 232;
    const float* wfc = w + 10;   // [5][2][2]
    const float* wfb = w + 30;   // [5][2]

#pragma unroll
    for (int i = 0; i < 4; ++i) {
        const size_t base = ((size_t)i * (size_t)B + (size_t)n) * 16;
        const float4* sp = (const float4*)(states + base);
        const float4 sv0 = sp[0], sv1 = sp[1], sv2 = sp[2], sv3 = sp[3];
        const float s[16] = { sv0.x, sv0.y, sv0.z, sv0.w,
                              sv1.x, sv1.y, sv1.z, sv1.w,
                              sv2.x, sv2.y, sv2.z, sv2.w,
                              sv3.x, sv3.y, sv3.z, sv3.w };
        float ns[16];
        float acc0 = 0.f, acc1 = 0.f;
#pragma unroll
        for (int hh = 0; hh < 2; ++hh) {
            const float u = hh ? h1 : h0;
            float acc = 0.f;
#pragma unroll
            for (int f = 0; f < 4; ++f) {
                const int idx = hh * 8 + f * 2;
                const float Ar = wA[i*16 + idx], Ai = wA[i*16 + idx + 1];
                const float Br = wB[i*16 + idx], Bi = wB[i*16 + idx + 1];
                const float Cr = wC[i*16 + idx], Ci = wC[i*16 + idx + 1];
                const float sr = s[idx], si = s[idx + 1];
                const float nr = Ar * sr - Ai * si + Br * u;
                const float ni = Ar * si + Ai * sr + Bi * u;
                ns[idx]     = nr;
                ns[idx + 1] = ni;
                acc += Cr * nr - Ci * ni;
            }
            if (hh) acc1 = acc; else acc0 = acc;
        }

        // y = 2*Re(C.ns) + u*D ; activation ; 2x2 fc
        float y0 = 2.f * acc0 + h0 * wD[i*2 + 0];
        float y1 = 2.f * acc1 + h1 * wD[i*2 + 1];
        y0 = (y0 >= 0.f) ? y0 : NEG_SLOPE * y0;
        y1 = (y1 >= 0.f) ? y1 : NEG_SLOPE * y1;
        const float nh0 = wfb[i*2 + 0] + wfc[i*4 + 0] * y0 + wfc[i*4 + 1] * y1;
        const float nh1 = wfb[i*2 + 1] + wfc[i*4 + 2] * y0 + wfc[i*4 + 3] * y1;
        h0 = nh0; h1 = nh1;

        float4* op = (float4*)(out_states + base);
        op[0] = make_float4(ns[0],  ns[1],  ns[2],  ns[3]);
        op[1] = make_float4(ns[4],  ns[5],  ns[6],  ns[7]);
        op[2] = make_float4(ns[8],  ns[9],  ns[10], ns[11]);
        op[3] = make_float4(ns[12], ns[13], ns[14], ns[15]);
    }

    // fc10
    const float o0 = wfb[8] + wfc[16] * h0 + wfc[17] * h1;
    const float o1 = wfb[9] + wfc[18] * h0 + wfc[19] * h1;
    ((float2*)out_h)[n] = make_float2(o0, o1);
}

extern "C" void kernel_launch(void* const* d_in, const int* in_sizes, int n_in,
                              void* d_out, int out_size, void* d_ws, size_t ws_size,
                              hipStream_t stream) {
    const float* x      = (const float*)d_in[0];
    const float* states = (const float*)d_in[1];
    const float* fc1_w  = (const float*)d_in[2];
    const float* fc1_b  = (const float*)d_in[3];
    const float* fc_w   = (const float*)d_in[4];
    const float* fc_b   = (const float*)d_in[5];
    const float* A      = (const float*)d_in[6];
    const float* Bm     = (const float*)d_in[7];
    const float* Cm     = (const float*)d_in[8];
    const float* Dm     = (const float*)d_in[9];
    const int B = in_sizes[0] / 4;

    float* out_h      = (float*)d_out;
    float* out_states = (float*)d_out + (size_t)2 * (size_t)B;

    dim3 grid((B + 255) / 256), block(256);
    hipLaunchKernelGGL(ssm_fused, grid, block, 0, stream,
                       x, states, fc1_w, fc1_b, fc_w, fc_b, A, Bm, Cm, Dm,
                       out_h, out_states, B);
}